// Round 1
// baseline (3328.638 us; speedup 1.0000x reference)
//
#include <hip/hip_runtime.h>
#include <hip/hip_bf16.h>

#define B_   4
#define L_   4096
#define D_   1024
#define DFF_ 4096
#define K_   2048

#define BM 128
#define BN 128
#define BK 8

__device__ __forceinline__ float gelu_tanh(float v) {
    float u = 0.7978845608028654f * (v + 0.044715f * v * v * v);
    return 0.5f * v * (1.0f + tanhf(u));
}

// ---------------- router scores: one wave per token, fp64 accumulate ----------------
__global__ __launch_bounds__(256) void score_kernel(
    const float* __restrict__ x, const float* __restrict__ wr,
    const float* __restrict__ br, float* __restrict__ scores)
{
    int gtid  = blockIdx.x * 256 + threadIdx.x;
    int token = gtid >> 6;
    int lane  = threadIdx.x & 63;
    if (token >= B_ * L_) return;
    const float* xr = x + (size_t)token * D_;
    double acc = 0.0;
    #pragma unroll
    for (int i = 0; i < 4; ++i) {
        int off = (lane + i * 64) * 4;
        float4 xv = *(const float4*)(xr + off);
        float4 wv = *(const float4*)(wr + off);
        acc += (double)xv.x * wv.x + (double)xv.y * wv.y +
               (double)xv.z * wv.z + (double)xv.w * wv.w;
    }
    #pragma unroll
    for (int off = 32; off > 0; off >>= 1)
        acc += __shfl_down(acc, off);
    if (lane == 0) scores[token] = (float)(acc + (double)br[0]);
}

// ---------------- rank per token (exact top-k with jax tie-break) ----------------
__global__ __launch_bounds__(256) void rank_kernel(
    const float* __restrict__ scores, int* __restrict__ sel)
{
    __shared__ float sc[L_];
    int b = blockIdx.y;
    int l = blockIdx.x * 256 + threadIdx.x;
    const float* sb = scores + b * L_;
    for (int i = threadIdx.x; i < L_; i += 256) sc[i] = sb[i];
    __syncthreads();
    float s = sc[l];
    int cnt = 0;
    for (int j = 0; j < L_; ++j) {
        float v = sc[j];
        cnt += (int)((v > s) || (v == s && j < l));
    }
    sel[b * L_ + l] = (cnt < K_) ? 1 : 0;
}

// ---------------- compact selected indices (ascending) ----------------
__global__ __launch_bounds__(256) void compact_kernel(
    const int* __restrict__ sel, int* __restrict__ idx)
{
    __shared__ int psum[256];
    int b = blockIdx.x, t = threadIdx.x;
    const int* sb = sel + b * L_;
    int base = t * 16;
    int flags[16]; int c = 0;
    #pragma unroll
    for (int i = 0; i < 16; ++i) { flags[i] = sb[base + i]; c += flags[i]; }
    psum[t] = c;
    __syncthreads();
    if (t == 0) {
        int acc = 0;
        for (int j = 0; j < 256; ++j) { int v = psum[j]; psum[j] = acc; acc += v; }
    }
    __syncthreads();
    int p = psum[t];
    #pragma unroll
    for (int i = 0; i < 16; ++i)
        if (flags[i]) idx[b * K_ + (p++)] = base + i;
}

// ---------------- GEMM1: h = gelu(gather(x) @ W1 + b1) ----------------
__global__ __launch_bounds__(256) void gemm1_kernel(
    const float* __restrict__ xb, const float* __restrict__ W1,
    const float* __restrict__ b1, const int* __restrict__ idxb,
    int row0, float* __restrict__ h)
{
    __shared__ float As[BK][BM];
    __shared__ float Bs[BK][BN];
    int tid = threadIdx.x;
    int bn = blockIdx.x * BN;
    int bm = blockIdx.y * BM;

    int mA = tid >> 1;
    int kA = (tid & 1) * 4;
    int tok = idxb[row0 + bm + mA];
    const float* aptr = xb + (size_t)tok * D_ + kA;

    int kB = tid >> 5;
    int nB = (tid & 31) * 4;
    const float* bptr = W1 + (size_t)kB * DFF_ + bn + nB;

    int tx = tid & 15, ty = tid >> 4;

    float acc[8][8];
    #pragma unroll
    for (int i = 0; i < 8; ++i)
        #pragma unroll
        for (int j = 0; j < 8; ++j) acc[i][j] = 0.f;

    for (int k0 = 0; k0 < D_; k0 += BK) {
        float4 av = *(const float4*)(aptr + k0);
        float4 bv = *(const float4*)(bptr + (size_t)k0 * DFF_);
        __syncthreads();
        As[kA + 0][mA] = av.x;
        As[kA + 1][mA] = av.y;
        As[kA + 2][mA] = av.z;
        As[kA + 3][mA] = av.w;
        *(float4*)&Bs[kB][nB] = bv;
        __syncthreads();
        #pragma unroll
        for (int kk = 0; kk < BK; ++kk) {
            float4 a0  = *(const float4*)&As[kk][ty * 8];
            float4 a1  = *(const float4*)&As[kk][ty * 8 + 4];
            float4 b0  = *(const float4*)&Bs[kk][tx * 4];
            float4 b1v = *(const float4*)&Bs[kk][64 + tx * 4];
            float a[8]  = {a0.x, a0.y, a0.z, a0.w, a1.x, a1.y, a1.z, a1.w};
            float bb[8] = {b0.x, b0.y, b0.z, b0.w, b1v.x, b1v.y, b1v.z, b1v.w};
            #pragma unroll
            for (int i = 0; i < 8; ++i)
                #pragma unroll
                for (int j = 0; j < 8; ++j)
                    acc[i][j] = fmaf(a[i], bb[j], acc[i][j]);
        }
    }
    #pragma unroll
    for (int i = 0; i < 8; ++i) {
        int r = bm + ty * 8 + i;
        float* hrow = h + (size_t)r * DFF_ + bn;
        #pragma unroll
        for (int half = 0; half < 2; ++half) {
            int c = half * 64 + tx * 4;
            float4 o;
            o.x = gelu_tanh(acc[i][half * 4 + 0] + b1[bn + c + 0]);
            o.y = gelu_tanh(acc[i][half * 4 + 1] + b1[bn + c + 1]);
            o.z = gelu_tanh(acc[i][half * 4 + 2] + b1[bn + c + 2]);
            o.w = gelu_tanh(acc[i][half * 4 + 3] + b1[bn + c + 3]);
            *(float4*)(hrow + c) = o;
        }
    }
}

// ---------------- GEMM2: out[tok] = h @ W2 + b2 (scatter) ----------------
__global__ __launch_bounds__(256) void gemm2_kernel(
    const float* __restrict__ h, const float* __restrict__ W2,
    const float* __restrict__ b2, const int* __restrict__ idxb,
    int row0, float* __restrict__ outb)
{
    __shared__ float As[BK][BM];
    __shared__ float Bs[BK][BN];
    int tid = threadIdx.x;
    int bn = blockIdx.x * BN;
    int bm = blockIdx.y * BM;

    int mA = tid >> 1;
    int kA = (tid & 1) * 4;
    const float* aptr = h + (size_t)(bm + mA) * DFF_ + kA;

    int kB = tid >> 5;
    int nB = (tid & 31) * 4;
    const float* bptr = W2 + (size_t)kB * D_ + bn + nB;

    int tx = tid & 15, ty = tid >> 4;

    float acc[8][8];
    #pragma unroll
    for (int i = 0; i < 8; ++i)
        #pragma unroll
        for (int j = 0; j < 8; ++j) acc[i][j] = 0.f;

    for (int k0 = 0; k0 < DFF_; k0 += BK) {
        float4 av = *(const float4*)(aptr + k0);
        float4 bv = *(const float4*)(bptr + (size_t)k0 * D_);
        __syncthreads();
        As[kA + 0][mA] = av.x;
        As[kA + 1][mA] = av.y;
        As[kA + 2][mA] = av.z;
        As[kA + 3][mA] = av.w;
        *(float4*)&Bs[kB][nB] = bv;
        __syncthreads();
        #pragma unroll
        for (int kk = 0; kk < BK; ++kk) {
            float4 a0  = *(const float4*)&As[kk][ty * 8];
            float4 a1  = *(const float4*)&As[kk][ty * 8 + 4];
            float4 b0  = *(const float4*)&Bs[kk][tx * 4];
            float4 b1v = *(const float4*)&Bs[kk][64 + tx * 4];
            float a[8]  = {a0.x, a0.y, a0.z, a0.w, a1.x, a1.y, a1.z, a1.w};
            float bb[8] = {b0.x, b0.y, b0.z, b0.w, b1v.x, b1v.y, b1v.z, b1v.w};
            #pragma unroll
            for (int i = 0; i < 8; ++i)
                #pragma unroll
                for (int j = 0; j < 8; ++j)
                    acc[i][j] = fmaf(a[i], bb[j], acc[i][j]);
        }
    }
    #pragma unroll
    for (int i = 0; i < 8; ++i) {
        int r = bm + ty * 8 + i;
        int tok = idxb[row0 + r];
        float* orow = outb + (size_t)tok * D_ + bn;
        #pragma unroll
        for (int half = 0; half < 2; ++half) {
            int c = half * 64 + tx * 4;
            float4 o;
            o.x = acc[i][half * 4 + 0] + b2[bn + c + 0];
            o.y = acc[i][half * 4 + 1] + b2[bn + c + 1];
            o.z = acc[i][half * 4 + 2] + b2[bn + c + 2];
            o.w = acc[i][half * 4 + 3] + b2[bn + c + 3];
            *(float4*)(orow + c) = o;
        }
    }
}

extern "C" void kernel_launch(void* const* d_in, const int* in_sizes, int n_in,
                              void* d_out, int out_size, void* d_ws, size_t ws_size,
                              hipStream_t stream)
{
    const float* x  = (const float*)d_in[0];
    const float* W1 = (const float*)d_in[1];
    const float* b1 = (const float*)d_in[2];
    const float* W2 = (const float*)d_in[3];
    const float* b2 = (const float*)d_in[4];
    const float* wr = (const float*)d_in[5];
    const float* br = (const float*)d_in[6];
    float* out = (float*)d_out;

    int*   idx    = (int*)d_ws;                          // B*K ints   (32 KB)
    float* scores = (float*)((char*)d_ws + (32 << 10));  // B*L floats (64 KB)
    int*   sel    = (int*)((char*)d_ws + (96 << 10));    // B*L ints   (64 KB)
    float* h      = (float*)((char*)d_ws + (256 << 10)); // row chunks of [RC, DFF]

    size_t havail = ws_size > (size_t)(256 << 10) ? ws_size - (size_t)(256 << 10) : 0;
    int RC = (int)(havail / ((size_t)DFF_ * sizeof(float)));
    RC = (RC / BM) * BM;
    if (RC > K_) RC = K_;
    if (RC < BM) RC = BM;

    hipMemsetAsync(d_out, 0, (size_t)B_ * L_ * D_ * sizeof(float), stream);
    score_kernel<<<dim3((B_ * L_) / 4), 256, 0, stream>>>(x, wr, br, scores);
    rank_kernel<<<dim3(L_ / 256, B_), 256, 0, stream>>>(scores, sel);
    compact_kernel<<<dim3(B_), 256, 0, stream>>>(sel, idx);

    for (int b = 0; b < B_; ++b) {
        const float* xb   = x   + (size_t)b * L_ * D_;
        float*       outb = out + (size_t)b * L_ * D_;
        const int*   idxb = idx + b * K_;
        for (int r0 = 0; r0 < K_; r0 += RC) {
            int rc = (K_ - r0 < RC) ? (K_ - r0) : RC;
            gemm1_kernel<<<dim3(DFF_ / BN, rc / BM), 256, 0, stream>>>(xb, W1, b1, idxb, r0, h);
            gemm2_kernel<<<dim3(D_ / BN, rc / BM), 256, 0, stream>>>(h, W2, b2, idxb, r0, outb);
        }
    }
}

// Round 2
// 335.030 us; speedup vs baseline: 9.9353x; 9.9353x over previous
//
#include <hip/hip_runtime.h>
#include <hip/hip_bf16.h>

#define B_   4
#define L_   4096
#define D_   1024
#define DFF_ 4096
#define K_   2048

typedef __attribute__((ext_vector_type(8))) short bf16x8;
typedef __attribute__((ext_vector_type(4))) float f32x4;

__device__ __forceinline__ unsigned short f2bf(float f) {
    unsigned u = __float_as_uint(f);
    u += 0x7fffu + ((u >> 16) & 1u);          // round-to-nearest-even
    return (unsigned short)(u >> 16);
}

__device__ __forceinline__ float gelu_fast(float v) {
    // gelu_tanh(v) == v * sigmoid(2 * 0.79788456*(v + 0.044715 v^3))
    float z = 1.5957691216057308f * v * (1.0f + 0.044715f * v * v);
    float e = __builtin_amdgcn_exp2f(-1.4426950408889634f * z);
    return v * __builtin_amdgcn_rcpf(1.0f + e);
}

__device__ __forceinline__ void gload_lds16(const void* g, void* l) {
    __builtin_amdgcn_global_load_lds(
        (const __attribute__((address_space(1))) void*)g,
        (__attribute__((address_space(3))) void*)l, 16, 0, 0);
}

// ---------------- router scores: one wave per token, fp64 accumulate ----------------
__global__ __launch_bounds__(256) void score_kernel(
    const float* __restrict__ x, const float* __restrict__ wr,
    const float* __restrict__ br, float* __restrict__ scores)
{
    int gtid  = blockIdx.x * 256 + threadIdx.x;
    int token = gtid >> 6;
    int lane  = threadIdx.x & 63;
    if (token >= B_ * L_) return;
    const float* xr = x + (size_t)token * D_;
    double acc = 0.0;
    #pragma unroll
    for (int i = 0; i < 4; ++i) {
        int off = (lane + i * 64) * 4;
        float4 xv = *(const float4*)(xr + off);
        float4 wv = *(const float4*)(wr + off);
        acc += (double)xv.x * wv.x + (double)xv.y * wv.y +
               (double)xv.z * wv.z + (double)xv.w * wv.w;
    }
    #pragma unroll
    for (int off = 32; off > 0; off >>= 1)
        acc += __shfl_down(acc, off);
    if (lane == 0) scores[token] = (float)(acc + (double)br[0]);
}

// ---------------- rank per token (exact top-k with jax tie-break) ----------------
__global__ __launch_bounds__(256) void rank_kernel(
    const float* __restrict__ scores, int* __restrict__ sel)
{
    __shared__ float sc[L_];
    int b = blockIdx.y;
    int l = blockIdx.x * 256 + threadIdx.x;
    const float* sb = scores + b * L_;
    for (int i = threadIdx.x; i < L_; i += 256) sc[i] = sb[i];
    __syncthreads();
    float s = sc[l];
    int cnt = 0;
    for (int j = 0; j < L_; ++j) {
        float v = sc[j];
        cnt += (int)((v > s) || (v == s && j < l));
    }
    sel[b * L_ + l] = (cnt < K_) ? 1 : 0;
}

// ---------------- compact selected indices (ascending) ----------------
__global__ __launch_bounds__(256) void compact_kernel(
    const int* __restrict__ sel, int* __restrict__ idx)
{
    __shared__ int psum[256];
    int b = blockIdx.x, t = threadIdx.x;
    const int* sb = sel + b * L_;
    int base = t * 16;
    int flags[16]; int c = 0;
    #pragma unroll
    for (int i = 0; i < 16; ++i) { flags[i] = sb[base + i]; c += flags[i]; }
    psum[t] = c;
    __syncthreads();
    if (t == 0) {
        int acc = 0;
        for (int j = 0; j < 256; ++j) { int v = psum[j]; psum[j] = acc; acc += v; }
    }
    __syncthreads();
    int p = psum[t];
    #pragma unroll
    for (int i = 0; i < 16; ++i)
        if (flags[i]) idx[b * K_ + (p++)] = base + i;
}

// ---------------- transpose + fp32->bf16: out[n][k] = bf16(in[k][n]) ----------------
__global__ __launch_bounds__(256) void transpose_bf16_kernel(
    const float* __restrict__ in, unsigned short* __restrict__ outb,
    int RK, int RN)
{
    __shared__ float t[32][33];
    int n0 = blockIdx.x * 32, k0 = blockIdx.y * 32;
    int tx = threadIdx.x & 31, ty = threadIdx.x >> 5;
    #pragma unroll
    for (int i = 0; i < 4; ++i)
        t[ty + 8 * i][tx] = in[(size_t)(k0 + ty + 8 * i) * RN + (n0 + tx)];
    __syncthreads();
    #pragma unroll
    for (int i = 0; i < 4; ++i)
        outb[(size_t)(n0 + ty + 8 * i) * RK + (k0 + tx)] = f2bf(t[tx][ty + 8 * i]);
}

// ---------------- gather selected rows, fp32->bf16 ----------------
__global__ __launch_bounds__(256) void gather_bf16_kernel(
    const float* __restrict__ x, const int* __restrict__ idxg,
    int row0, unsigned short* __restrict__ xsel)
{
    int rl = blockIdx.x;
    int grow = row0 + rl;
    int tok = idxg[grow];
    int bb = grow >> 11;                       // K_ = 2048
    const float* src = x + ((size_t)bb * L_ + (size_t)tok) * D_;
    int t = threadIdx.x;
    float4 v = *(const float4*)(src + t * 4);
    ushort4 o;
    o.x = f2bf(v.x); o.y = f2bf(v.y); o.z = f2bf(v.z); o.w = f2bf(v.w);
    *(ushort4*)(xsel + (size_t)rl * D_ + t * 4) = o;
}

// ---------------- m97-style bf16 MFMA GEMM: C[128x128] per block ----------------
// A: [Mc][KD] bf16, row-major.  Bm: [ND][KD] bf16 (n-major, i.e. B^T).
// EPI 0: h[row][col] = bf16(gelu(acc + bias[col]))   (ND = DFF_)
// EPI 1: out[b][tok][col] = acc + bias[col]          (ND = D_, scatter)
template<int KD, int EPI>
__global__ __launch_bounds__(256) void gemm_bf16_kernel(
    const unsigned short* __restrict__ A,
    const unsigned short* __restrict__ Bm,
    const float* __restrict__ bias,
    unsigned short* __restrict__ hout,
    float* __restrict__ outp,
    const int* __restrict__ idxg, int row0)
{
    __shared__ unsigned short As[128][32];
    __shared__ unsigned short Bs[128][32];

    const int tid  = threadIdx.x;
    const int lane = tid & 63;
    const int wave = tid >> 6;
    const int wm = wave >> 1, wn = wave & 1;
    const int bm = blockIdx.y * 128;
    const int bn = blockIdx.x * 128;

    // staging: chunk c (16B) -> LDS row c>>2, elem col (c&3)*8 ; global row bm+(c>>2)
    const int c0 = wave * 128 + lane;
    const int rS = c0 >> 2;
    const int kS = (c0 & 3) * 8;
    const unsigned short* srcA0 = A  + (size_t)(bm + rS) * KD + kS;
    const unsigned short* srcA1 = srcA0 + (size_t)16 * KD;
    const unsigned short* srcB0 = Bm + (size_t)(bn + rS) * KD + kS;
    const unsigned short* srcB1 = srcB0 + (size_t)16 * KD;
    unsigned short* dstA0 = &As[0][0] + wave * 1024;   // bytes: wave*2048
    unsigned short* dstA1 = dstA0 + 512;
    unsigned short* dstB0 = &Bs[0][0] + wave * 1024;
    unsigned short* dstB1 = dstB0 + 512;

    // fragment read addresses
    const int fr = lane & 15;
    const int kq = (lane >> 4) * 8;
    const unsigned short* apA = &As[wm * 64 + fr][0] + kq;
    const unsigned short* apB = &Bs[wn * 64 + fr][0] + kq;

    f32x4 acc[4][4];
    #pragma unroll
    for (int i = 0; i < 4; ++i)
        #pragma unroll
        for (int j = 0; j < 4; ++j)
            acc[i][j] = (f32x4)0.0f;

    for (int k0 = 0; k0 < KD; k0 += 32) {
        gload_lds16(srcA0 + k0, dstA0);
        gload_lds16(srcA1 + k0, dstA1);
        gload_lds16(srcB0 + k0, dstB0);
        gload_lds16(srcB1 + k0, dstB1);
        __syncthreads();                       // drains vmcnt(0) then barrier
        bf16x8 af[4], bfv[4];
        #pragma unroll
        for (int i = 0; i < 4; ++i) {
            af[i]  = *(const bf16x8*)(apA + i * 512);   // i*16 rows * 32
            bfv[i] = *(const bf16x8*)(apB + i * 512);
        }
        #pragma unroll
        for (int mi = 0; mi < 4; ++mi)
            #pragma unroll
            for (int ni = 0; ni < 4; ++ni)
                acc[mi][ni] = __builtin_amdgcn_mfma_f32_16x16x32_bf16(
                    af[mi], bfv[ni], acc[mi][ni], 0, 0, 0);
        __syncthreads();
    }

    // epilogue: C/D layout col = lane&15, row = (lane>>4)*4 + reg
    const int mB = bm + wm * 64;
    const int nB = bn + wn * 64;
    const int rq = (lane >> 4) * 4;
    #pragma unroll
    for (int ni = 0; ni < 4; ++ni) {
        const int col = nB + ni * 16 + fr;
        const float bc = bias[col];
        #pragma unroll
        for (int mi = 0; mi < 4; ++mi) {
            const int rbase = mB + mi * 16 + rq;
            f32x4 v = acc[mi][ni];
            #pragma unroll
            for (int r = 0; r < 4; ++r) {
                float val = v[r] + bc;
                if (EPI == 0) {
                    hout[(size_t)(rbase + r) * DFF_ + col] = f2bf(gelu_fast(val));
                } else {
                    int grow = row0 + rbase + r;
                    int bb = grow >> 11;
                    int tok = idxg[grow];
                    outp[((size_t)bb * L_ + (size_t)tok) * D_ + col] = val;
                }
            }
        }
    }
}

extern "C" void kernel_launch(void* const* d_in, const int* in_sizes, int n_in,
                              void* d_out, int out_size, void* d_ws, size_t ws_size,
                              hipStream_t stream)
{
    const float* x  = (const float*)d_in[0];
    const float* W1 = (const float*)d_in[1];
    const float* b1 = (const float*)d_in[2];
    const float* W2 = (const float*)d_in[3];
    const float* b2 = (const float*)d_in[4];
    const float* wr = (const float*)d_in[5];
    const float* br = (const float*)d_in[6];
    float* out = (float*)d_out;

    char* ws = (char*)d_ws;
    int*   idx    = (int*)ws;                          // 32 KB
    float* scores = (float*)(ws + (32 << 10));         // 64 KB
    int*   sel    = (int*)(ws + (96 << 10));           // 64 KB
    unsigned short* W1T = (unsigned short*)(ws + (256 << 10));   // [DFF][D] bf16, 8 MB
    unsigned short* W2T = W1T + (size_t)DFF_ * D_;               // [D][DFF] bf16, 8 MB

    size_t fixedB = (size_t)(256 << 10) + (size_t)DFF_ * D_ * 2 * 2;
    size_t avail  = ws_size > fixedB ? ws_size - fixedB : 0;
    int RC = (int)(avail / (size_t)(D_ * 2 + DFF_ * 2));  // 10240 B per row
    RC = (RC / 128) * 128;
    if (RC > B_ * K_) RC = B_ * K_;
    if (RC < 128) RC = 128;
    unsigned short* xsel = (unsigned short*)(ws + fixedB);       // [RC][D] bf16
    unsigned short* hbuf = xsel + (size_t)RC * D_;               // [RC][DFF] bf16

    hipMemsetAsync(d_out, 0, (size_t)B_ * L_ * D_ * sizeof(float), stream);
    score_kernel<<<dim3((B_ * L_) / 4), 256, 0, stream>>>(x, wr, br, scores);
    rank_kernel<<<dim3(L_ / 256, B_), 256, 0, stream>>>(scores, sel);
    compact_kernel<<<dim3(B_), 256, 0, stream>>>(sel, idx);
    transpose_bf16_kernel<<<dim3(DFF_ / 32, D_ / 32), 256, 0, stream>>>(W1, W1T, D_, DFF_);
    transpose_bf16_kernel<<<dim3(D_ / 32, DFF_ / 32), 256, 0, stream>>>(W2, W2T, DFF_, D_);

    for (int r0 = 0; r0 < B_ * K_; r0 += RC) {
        int rc = (B_ * K_ - r0 < RC) ? (B_ * K_ - r0) : RC;
        gather_bf16_kernel<<<dim3(rc), 256, 0, stream>>>(x, idx, r0, xsel);
        gemm_bf16_kernel<D_, 0><<<dim3(DFF_ / 128, rc / 128), 256, 0, stream>>>(
            xsel, W1T, b1, hbuf, nullptr, nullptr, 0);
        gemm_bf16_kernel<DFF_, 1><<<dim3(D_ / 128, rc / 128), 256, 0, stream>>>(
            hbuf, W2T, b2, nullptr, out, idx, r0);
    }
}

// Round 3
// 318.766 us; speedup vs baseline: 10.4423x; 1.0510x over previous
//
#include <hip/hip_runtime.h>
#include <hip/hip_bf16.h>

#define B_   4
#define L_   4096
#define D_   1024
#define DFF_ 4096
#define K_   2048

typedef __attribute__((ext_vector_type(8))) short bf16x8;
typedef __attribute__((ext_vector_type(4))) float f32x4;
typedef unsigned short u16;

__device__ __forceinline__ u16 f2bf(float f) {
    unsigned u = __float_as_uint(f);
    u += 0x7fffu + ((u >> 16) & 1u);          // round-to-nearest-even
    return (u16)(u >> 16);
}

__device__ __forceinline__ float gelu_fast(float v) {
    float z = 1.5957691216057308f * v * (1.0f + 0.044715f * v * v);
    float e = __builtin_amdgcn_exp2f(-1.4426950408889634f * z);
    return v * __builtin_amdgcn_rcpf(1.0f + e);
}

__device__ __forceinline__ void gload_lds16(const void* g, void* l) {
    __builtin_amdgcn_global_load_lds(
        (const __attribute__((address_space(1))) void*)g,
        (__attribute__((address_space(3))) void*)l, 16, 0, 0);
}

// ---------------- router scores ----------------
__global__ __launch_bounds__(256) void score_kernel(
    const float* __restrict__ x, const float* __restrict__ wr,
    const float* __restrict__ br, float* __restrict__ scores)
{
    int gtid  = blockIdx.x * 256 + threadIdx.x;
    int token = gtid >> 6;
    int lane  = threadIdx.x & 63;
    if (token >= B_ * L_) return;
    const float* xr = x + (size_t)token * D_;
    double acc = 0.0;
    #pragma unroll
    for (int i = 0; i < 4; ++i) {
        int off = (lane + i * 64) * 4;
        float4 xv = *(const float4*)(xr + off);
        float4 wv = *(const float4*)(wr + off);
        acc += (double)xv.x * wv.x + (double)xv.y * wv.y +
               (double)xv.z * wv.z + (double)xv.w * wv.w;
    }
    #pragma unroll
    for (int off = 32; off > 0; off >>= 1)
        acc += __shfl_down(acc, off);
    if (lane == 0) scores[token] = (float)(acc + (double)br[0]);
}

// ---------------- rank per token (exact top-k, jax tie-break) ----------------
__global__ __launch_bounds__(256) void rank_kernel(
    const float* __restrict__ scores, int* __restrict__ sel)
{
    __shared__ float sc[L_];
    int b = blockIdx.y;
    int l = blockIdx.x * 256 + threadIdx.x;
    const float* sb = scores + b * L_;
    for (int i = threadIdx.x; i < L_; i += 256) sc[i] = sb[i];
    __syncthreads();
    float s = sc[l];
    int cnt = 0;
    for (int j = 0; j < L_; ++j) {
        float v = sc[j];
        cnt += (int)((v > s) || (v == s && j < l));
    }
    sel[b * L_ + l] = (cnt < K_) ? 1 : 0;
}

// ---------------- compact selected indices (ascending) ----------------
__global__ __launch_bounds__(256) void compact_kernel(
    const int* __restrict__ sel, int* __restrict__ idx)
{
    __shared__ int psum[256];
    int b = blockIdx.x, t = threadIdx.x;
    const int* sb = sel + b * L_;
    int base = t * 16;
    int flags[16]; int c = 0;
    #pragma unroll
    for (int i = 0; i < 16; ++i) { flags[i] = sb[base + i]; c += flags[i]; }
    psum[t] = c;
    __syncthreads();
    if (t == 0) {
        int acc = 0;
        for (int j = 0; j < 256; ++j) { int v = psum[j]; psum[j] = acc; acc += v; }
    }
    __syncthreads();
    int p = psum[t];
    #pragma unroll
    for (int i = 0; i < 16; ++i)
        if (flags[i]) idx[b * K_ + (p++)] = base + i;
}

// ---------------- zero unselected output rows (replaces full memset) ----------------
__global__ __launch_bounds__(256) void zero_unsel_kernel(
    const int* __restrict__ sel, float* __restrict__ out)
{
    int row = blockIdx.x;
    if (sel[row]) return;
    float4 z = make_float4(0.f, 0.f, 0.f, 0.f);
    *(float4*)(out + (size_t)row * D_ + threadIdx.x * 4) = z;
}

// ---------------- transpose + fp32->bf16: out[n][k] = bf16(in[k][n]) ----------------
__global__ __launch_bounds__(256) void transpose_bf16_kernel(
    const float* __restrict__ in, u16* __restrict__ outb, int RK, int RN)
{
    __shared__ float t[32][33];
    int n0 = blockIdx.x * 32, k0 = blockIdx.y * 32;
    int tx = threadIdx.x & 31, ty = threadIdx.x >> 5;
    #pragma unroll
    for (int i = 0; i < 4; ++i)
        t[ty + 8 * i][tx] = in[(size_t)(k0 + ty + 8 * i) * RN + (n0 + tx)];
    __syncthreads();
    #pragma unroll
    for (int i = 0; i < 4; ++i)
        outb[(size_t)(n0 + ty + 8 * i) * RK + (k0 + tx)] = f2bf(t[tx][ty + 8 * i]);
}

// ---------------- gather selected rows, fp32->bf16 ----------------
__global__ __launch_bounds__(256) void gather_bf16_kernel(
    const float* __restrict__ x, const int* __restrict__ idxg,
    int row0, u16* __restrict__ xsel)
{
    int rl = blockIdx.x;
    int grow = row0 + rl;
    int tok = idxg[grow];
    int bb = grow >> 11;
    const float* src = x + ((size_t)bb * L_ + (size_t)tok) * D_;
    int t = threadIdx.x;
    float4 v = *(const float4*)(src + t * 4);
    ushort4 o;
    o.x = f2bf(v.x); o.y = f2bf(v.y); o.z = f2bf(v.z); o.w = f2bf(v.w);
    *(ushort4*)(xsel + (size_t)rl * D_ + t * 4) = o;
}

// ======================= gemm1: 256x256 8-phase (T3+T4+T5) =======================
// A: xsel [M][1024] bf16.  Bm: W1T [4096][1024] bf16 (n-major).
// h[row][col] = bf16(gelu(acc + b1[col])).  K=1024 -> NT=16 K-tiles, 8 iterations.
#define G1_NT 16

__device__ __forceinline__ void wait_vm4() {
    asm volatile("s_waitcnt vmcnt(4)" ::: "memory");
    __builtin_amdgcn_sched_barrier(0);
}
__device__ __forceinline__ void wait_vm0() {
    asm volatile("s_waitcnt vmcnt(0)" ::: "memory");
    __builtin_amdgcn_sched_barrier(0);
}

__global__ __launch_bounds__(512, 2) void gemm1_8ph_kernel(
    const u16* __restrict__ A, const u16* __restrict__ Bm,
    const float* __restrict__ bias, u16* __restrict__ hout)
{
    // LDS: [dbuf][khalf] slots of [256 rows][32 k] bf16, A and B. 128 KiB total.
    __shared__ u16 AsArr[2][2][256 * 32];
    __shared__ u16 BsArr[2][2][256 * 32];

    const int tid  = threadIdx.x;
    const int lane = tid & 63;
    const int wid  = tid >> 6;
    const int wm = wid >> 2, wn = wid & 3;     // 2M x 4N waves
    const int fr = lane & 15;
    const int kq = (lane >> 4) * 8;
    const int rq = (lane >> 4) * 4;

    // XCD-aware swizzle (nwg = 16 * (M/256), always % 8 == 0)
    const int nwg = gridDim.x;
    const int o   = blockIdx.x;
    const int swz = (o & 7) * (nwg >> 3) + (o >> 3);
    const int bn  = (swz & 15) * 256;          // N tile (gx = 4096/256 = 16)
    const int bm  = (swz >> 4) * 256;          // M tile

    // staging thread-invariants: chunk c=tid -> row c>>2, kcol (c&3)*8 ; chunk2 = +512
    const int srow = tid >> 2;
    const int skof = (tid & 3) * 8;
    const u16* Abase = A  + (size_t)(bm + srow) * D_ + skof;
    const u16* Bbase = Bm + (size_t)(bn + srow) * D_ + skof;
    u16* AsFlat = &AsArr[0][0][0];
    u16* BsFlat = &BsArr[0][0][0];

    f32x4 acc[8][4];
    #pragma unroll
    for (int m = 0; m < 8; ++m)
        #pragma unroll
        for (int n = 0; n < 4; ++n) acc[m][n] = (f32x4)0.0f;

    // stage half-tile s: kt=s>>2, j=s&3 {0:Ak0,1:Bk0,2:Ak1,3:Bk1}
    auto stage = [&](int s) {
        int kt = s >> 2, j = s & 3;
        int d = kt & 1, h = j >> 1;
        int koff = kt * 64 + h * 32;
        if (j & 1) {
            u16* dst = BsFlat + (d * 2 + h) * 8192 + tid * 8;
            gload_lds16(Bbase + koff, dst);
            gload_lds16(Bbase + koff + (size_t)128 * D_, dst + 4096);
        } else {
            u16* dst = AsFlat + (d * 2 + h) * 8192 + tid * 8;
            gload_lds16(Abase + koff, dst);
            gload_lds16(Abase + koff + (size_t)128 * D_, dst + 4096);
        }
    };

    // prologue: stage halves 0..5 (K-tile0 full + K-tile1 k0-halves)
    #pragma unroll
    for (int s = 0; s < 6; ++s) stage(s);
    wait_vm4();                                // halves 0..3 (kt0) complete
    __builtin_amdgcn_s_barrier();

    bf16x8 bfv[4];
    for (int i = 0; i < G1_NT / 2; ++i) {
        #pragma unroll
        for (int p = 0; p < 8; ++p) {
            const int kt  = 2 * i + (p >> 2);
            const int d   = kt & 1;
            const int kh  = (p >> 1) & 1;
            const int mlo = (p & 1) * 4;
            // ds_reads: B-frags on even sub-phase, A-frags always
            if ((p & 1) == 0) {
                #pragma unroll
                for (int n = 0; n < 4; ++n)
                    bfv[n] = *(const bf16x8*)(&BsArr[d][kh][0] +
                              (wn * 64 + n * 16 + fr) * 32 + kq);
            }
            bf16x8 af[4];
            #pragma unroll
            for (int q = 0; q < 4; ++q)
                af[q] = *(const bf16x8*)(&AsArr[d][kh][0] +
                          (wm * 128 + (mlo + q) * 16 + fr) * 32 + kq);
            // stage one half-tile, 6 ahead
            int s = 8 * i + p + 6;
            if (s < 4 * G1_NT) stage(s);
            __builtin_amdgcn_s_barrier();
            asm volatile("s_waitcnt lgkmcnt(0)" ::: "memory");
            __builtin_amdgcn_sched_barrier(0);
            __builtin_amdgcn_s_setprio(1);
            #pragma unroll
            for (int q = 0; q < 4; ++q)
                #pragma unroll
                for (int n = 0; n < 4; ++n)
                    acc[mlo + q][n] = __builtin_amdgcn_mfma_f32_16x16x32_bf16(
                        af[q], bfv[n], acc[mlo + q][n], 0, 0, 0);
            __builtin_amdgcn_s_setprio(0);
            // K-tile boundary waits: counted vmcnt, drain 0 only entering last tile
            if (p == 3) {
                if (i == G1_NT / 2 - 1) wait_vm0(); else wait_vm4();
            } else if (p == 7) {
                if (i < G1_NT / 2 - 1) wait_vm4();
            }
            __builtin_amdgcn_s_barrier();
        }
    }

    // epilogue: bias + gelu -> bf16 h
    #pragma unroll
    for (int n = 0; n < 4; ++n) {
        const int col = bn + wn * 64 + n * 16 + fr;
        const float bc = bias[col];
        #pragma unroll
        for (int m = 0; m < 8; ++m) {
            const int rbase = bm + wm * 128 + m * 16 + rq;
            #pragma unroll
            for (int r = 0; r < 4; ++r)
                hout[(size_t)(rbase + r) * DFF_ + col] =
                    f2bf(gelu_fast(acc[m][n][r] + bc));
        }
    }
}

// ======================= gemm2: proven 128x128 m97 + XCD swizzle =======================
// A: h [M][4096] bf16.  Bm: W2T [1024][4096] bf16.  Scatter-write fp32 out + b2.
__global__ __launch_bounds__(256) void gemm2_kernel(
    const u16* __restrict__ A, const u16* __restrict__ Bm,
    const float* __restrict__ bias, float* __restrict__ outp,
    const int* __restrict__ idxg, int row0)
{
    __shared__ u16 As[128][32];
    __shared__ u16 Bs[128][32];

    const int tid  = threadIdx.x;
    const int lane = tid & 63;
    const int wave = tid >> 6;
    const int wm = wave >> 1, wn = wave & 1;

    const int nwg = gridDim.x;
    const int o   = blockIdx.x;
    const int swz = (o & 7) * (nwg >> 3) + (o >> 3);
    const int bn  = (swz & 7) * 128;          // gx = 1024/128 = 8
    const int bm  = (swz >> 3) * 128;

    const int c0 = wave * 128 + lane;
    const int rS = c0 >> 2;
    const int kS = (c0 & 3) * 8;
    const u16* srcA0 = A  + (size_t)(bm + rS) * DFF_ + kS;
    const u16* srcA1 = srcA0 + (size_t)16 * DFF_;
    const u16* srcB0 = Bm + (size_t)(bn + rS) * DFF_ + kS;
    const u16* srcB1 = srcB0 + (size_t)16 * DFF_;
    u16* dstA0 = &As[0][0] + wave * 1024;
    u16* dstA1 = dstA0 + 512;
    u16* dstB0 = &Bs[0][0] + wave * 1024;
    u16* dstB1 = dstB0 + 512;

    const int fr = lane & 15;
    const int kq = (lane >> 4) * 8;
    const u16* apA = &As[wm * 64 + fr][0] + kq;
    const u16* apB = &Bs[wn * 64 + fr][0] + kq;

    f32x4 acc[4][4];
    #pragma unroll
    for (int i = 0; i < 4; ++i)
        #pragma unroll
        for (int j = 0; j < 4; ++j)
            acc[i][j] = (f32x4)0.0f;

    for (int k0 = 0; k0 < DFF_; k0 += 32) {
        gload_lds16(srcA0 + k0, dstA0);
        gload_lds16(srcA1 + k0, dstA1);
        gload_lds16(srcB0 + k0, dstB0);
        gload_lds16(srcB1 + k0, dstB1);
        __syncthreads();
        bf16x8 af[4], bfv[4];
        #pragma unroll
        for (int i = 0; i < 4; ++i) {
            af[i]  = *(const bf16x8*)(apA + i * 512);
            bfv[i] = *(const bf16x8*)(apB + i * 512);
        }
        #pragma unroll
        for (int mi = 0; mi < 4; ++mi)
            #pragma unroll
            for (int ni = 0; ni < 4; ++ni)
                acc[mi][ni] = __builtin_amdgcn_mfma_f32_16x16x32_bf16(
                    af[mi], bfv[ni], acc[mi][ni], 0, 0, 0);
        __syncthreads();
    }

    const int mB = bm + wm * 64;
    const int nB = bn + wn * 64;
    const int rq = (lane >> 4) * 4;
    #pragma unroll
    for (int ni = 0; ni < 4; ++ni) {
        const int col = nB + ni * 16 + fr;
        const float bc = bias[col];
        #pragma unroll
        for (int mi = 0; mi < 4; ++mi) {
            const int rbase = mB + mi * 16 + rq;
            f32x4 v = acc[mi][ni];
            #pragma unroll
            for (int r = 0; r < 4; ++r) {
                int grow = row0 + rbase + r;
                int bb = grow >> 11;
                int tok = idxg[grow];
                outp[((size_t)bb * L_ + (size_t)tok) * D_ + col] = v[r] + bc;
            }
        }
    }
}

extern "C" void kernel_launch(void* const* d_in, const int* in_sizes, int n_in,
                              void* d_out, int out_size, void* d_ws, size_t ws_size,
                              hipStream_t stream)
{
    const float* x  = (const float*)d_in[0];
    const float* W1 = (const float*)d_in[1];
    const float* b1 = (const float*)d_in[2];
    const float* W2 = (const float*)d_in[3];
    const float* b2 = (const float*)d_in[4];
    const float* wr = (const float*)d_in[5];
    const float* br = (const float*)d_in[6];
    float* out = (float*)d_out;

    char* ws = (char*)d_ws;
    int*   idx    = (int*)ws;                          // 32 KB
    float* scores = (float*)(ws + (32 << 10));         // 64 KB
    int*   sel    = (int*)(ws + (96 << 10));           // 64 KB
    u16* W1T = (u16*)(ws + (256 << 10));               // [4096][1024] bf16, 8 MB
    u16* W2T = W1T + (size_t)DFF_ * D_;                // [1024][4096] bf16, 8 MB

    size_t fixedB = (size_t)(256 << 10) + (size_t)DFF_ * D_ * 2 * 2;
    size_t avail  = ws_size > fixedB ? ws_size - fixedB : 0;
    int RC = (int)(avail / (size_t)(D_ * 2 + DFF_ * 2));
    RC = (RC / 256) * 256;
    if (RC > B_ * K_) RC = B_ * K_;
    if (RC < 256) RC = 256;
    u16* xsel = (u16*)(ws + fixedB);                   // [RC][1024] bf16
    u16* hbuf = xsel + (size_t)RC * D_;                // [RC][4096] bf16

    score_kernel<<<dim3((B_ * L_) / 4), 256, 0, stream>>>(x, wr, br, scores);
    rank_kernel<<<dim3(L_ / 256, B_), 256, 0, stream>>>(scores, sel);
    compact_kernel<<<dim3(B_), 256, 0, stream>>>(sel, idx);
    zero_unsel_kernel<<<dim3(B_ * L_), 256, 0, stream>>>(sel, out);
    transpose_bf16_kernel<<<dim3(DFF_ / 32, D_ / 32), 256, 0, stream>>>(W1, W1T, D_, DFF_);
    transpose_bf16_kernel<<<dim3(D_ / 32, DFF_ / 32), 256, 0, stream>>>(W2, W2T, DFF_, D_);

    for (int r0 = 0; r0 < B_ * K_; r0 += RC) {
        int rc = (B_ * K_ - r0 < RC) ? (B_ * K_ - r0) : RC;
        gather_bf16_kernel<<<dim3(rc), 256, 0, stream>>>(x, idx, r0, xsel);
        gemm1_8ph_kernel<<<dim3((DFF_ / 256) * (rc / 256)), 512, 0, stream>>>(
            xsel, W1T, b1, hbuf);
        gemm2_kernel<<<dim3((D_ / 128) * (rc / 128)), 256, 0, stream>>>(
            hbuf, W2T, b2, out, idx, r0);
    }
}